// Round 7
// baseline (240.962 us; speedup 1.0000x reference)
//
#include <hip/hip_runtime.h>
#include <cstdint>
#include <cstddef>

#define NB 8
#define NN 65536
#define NS (NN + 16)         // sorted-buffer row stride (row NN = zero sentinel)
#define GG 64
#define GG3 (GG*GG*GG)
#define NW (GG3/32)          // 8192 mask words per batch
#define NBLKC 2048           // conv blocks (6/CU by LDS; 2 pairs per wave)
#define NP32 (NB * 2048)     // 32-voxel tile-pairs total
#define EPSC 1e-3f

typedef __bf16 bf16x8 __attribute__((ext_vector_type(8)));
typedef float  f32x4  __attribute__((ext_vector_type(4)));

__device__ __forceinline__ unsigned short f2bf(float f) {
    unsigned u = __builtin_bit_cast(unsigned, f);
    unsigned r = (u + 0x7fffu + ((u >> 16) & 1u)) >> 16;
    return (unsigned short)r;
}
__device__ __forceinline__ unsigned pk2(float a, float b) {
    return (unsigned)f2bf(a) | ((unsigned)f2bf(b) << 16);
}
__device__ __forceinline__ float bf2f(unsigned short s) {
    return __builtin_bit_cast(float, (unsigned)s << 16);
}

__device__ __forceinline__ int site_rank2(const int2* __restrict__ mwb, int lin) {
    int2 mw = mwb[lin >> 5];
    uint32_t w = (uint32_t)mw.x;
    uint32_t bit = 1u << (lin & 31);
    if (!(w & bit)) return -1;
    return mw.y + __popc(w & (bit - 1u));
}

// ---------------------------------------------------------------------------
// K1: occupancy bitmask (mask pre-memset 0) + weight-fragment packing fused.
// wf[s][i][lane][j] = w_s[off=2i+(quad>>1)][c=(quad&1)*8+j][n=lane&15]
// ---------------------------------------------------------------------------
__global__ __launch_bounds__(256) void build_mask_kernel(
    const int* __restrict__ xyz, const int* __restrict__ nvv,
    uint32_t* __restrict__ mask,
    const float* __restrict__ w0, const float* __restrict__ w1,
    unsigned short* __restrict__ wf)
{
    int b = blockIdx.y;
    int n = blockIdx.x * 256 + threadIdx.x;
    if (n < nvv[b]) {
        const int* cp = xyz + ((size_t)b * NN + n) * 3;
        int lin = cp[0] * (GG * GG) + cp[1] * GG + cp[2];
        atomicOr(&mask[b * NW + (lin >> 5)], 1u << (lin & 31));
    }
    // fused weight packing on blocks (x==0, y<2)
    if (blockIdx.x == 0 && b < 2) {
        const float* w = b ? w1 : w0;
        unsigned short* o = wf + b * 14 * 512;
        for (int idx = threadIdx.x; idx < 14 * 512; idx += 256) {
            int i = idx >> 9;
            int rem = idx & 511;
            int L = rem >> 3, j = rem & 7;
            int quad = L >> 4, nn = L & 15;
            int off = 2 * i + (quad >> 1);
            int c = ((quad & 1) << 3) + j;
            float v = (off < 27) ? w[(off * 16 + c) * 16 + nn] : 0.f;
            o[idx] = f2bf(v);
        }
    }
}

// ---------------------------------------------------------------------------
// K2: exclusive prefix sum of popcounts -> combined int2 {mask_word, base}
// ---------------------------------------------------------------------------
__global__ __launch_bounds__(256) void scan_mask_kernel(
    const uint32_t* __restrict__ mask, int2* __restrict__ mwb)
{
    int b = blockIdx.x;
    const uint32_t* mb = mask + (size_t)b * NW;
    int2* wb = mwb + (size_t)b * NW;
    int t = threadIdx.x;

    uint32_t wv[32];
    int cnts[32];
    int local = 0;
    #pragma unroll
    for (int i = 0; i < 32; i++) {
        wv[i] = mb[t * 32 + i];
        cnts[i] = __popc(wv[i]);
        local += cnts[i];
    }

    __shared__ int sc[256];
    sc[t] = local;
    __syncthreads();
    for (int off = 1; off < 256; off <<= 1) {
        int v = (t >= off) ? sc[t - off] : 0;
        __syncthreads();
        sc[t] += v;
        __syncthreads();
    }
    int base = sc[t] - local;   // exclusive
    #pragma unroll
    for (int i = 0; i < 32; i++) {
        wb[t * 32 + i] = make_int2((int)wv[i], base);
        base += cnts[i];
    }
}

// ---------------------------------------------------------------------------
// K3: permutation + gather feats (fp32) into rank-sorted bf16 rows.
// srow[r] = {lin, original n}. Rows [cnt, NN] zeroed (row NN = sentinel).
// ---------------------------------------------------------------------------
__global__ __launch_bounds__(256) void perm_gather_kernel(
    const int* __restrict__ xyz, const int* __restrict__ nvv,
    const int2* __restrict__ mwb,
    const float* __restrict__ feats,
    int2* __restrict__ srow,
    unsigned short* __restrict__ sfeats)
{
    int b = blockIdx.y;
    int n = blockIdx.x * 256 + threadIdx.x;
    int cnt = nvv[b];
    unsigned short* sfb = sfeats + (size_t)b * NS * 16;
    if (blockIdx.x == 0 && threadIdx.x < 16)
        sfb[(size_t)NN * 16 + threadIdx.x] = 0;     // sentinel row
    if (n < cnt) {
        const int* cp = xyz + ((size_t)b * NN + n) * 3;
        int lin = cp[0] * (GG * GG) + cp[1] * GG + cp[2];
        int r = site_rank2(mwb + (size_t)b * NW, lin);
        srow[(size_t)b * NN + r] = make_int2(lin, n);
        const float4* fp = (const float4*)(feats + ((size_t)b * NN + n) * 16);
        float4 f0 = fp[0], f1 = fp[1], f2 = fp[2], f3 = fp[3];
        uint4 lo = make_uint4(pk2(f0.x, f0.y), pk2(f0.z, f0.w),
                              pk2(f1.x, f1.y), pk2(f1.z, f1.w));
        uint4 hi = make_uint4(pk2(f2.x, f2.y), pk2(f2.z, f2.w),
                              pk2(f3.x, f3.y), pk2(f3.z, f3.w));
        *(uint4*)(sfb + (size_t)r * 16)     = lo;
        *(uint4*)(sfb + (size_t)r * 16 + 8) = hi;
    } else {
        uint4 z = make_uint4(0, 0, 0, 0);
        *(uint4*)(sfb + (size_t)n * 16)     = z;
        *(uint4*)(sfb + (size_t)n * 16 + 8) = z;
    }
}

// ---------------------------------------------------------------------------
// K4/K6: MFMA sparse conv, pair-of-tiles (32 ranks) per wave iteration.
// Rank phase: one mask gather per (voxel, 3x3 column); 3 dz ranks derived
// from one word (+rare predicated 2nd word at z%32 boundaries).
// Epilogue: LDS-transposed, one coalesced 1KB store per pair.
// Output: sorted bf16 pre-BN rows. BN stats via 16-way striped atomics.
// ---------------------------------------------------------------------------
__global__ __launch_bounds__(256, 4) void conv_mfma_kernel(
    const unsigned short* __restrict__ sfeats,  // (B,NS,16) bf16 rank-sorted
    const int2*     __restrict__ srow,          // (B,NN) rank -> {lin, n}
    const int*      __restrict__ nvv,
    const int2*     __restrict__ mwb,           // (B,NW) {mask word, base}
    const unsigned short* __restrict__ wfrag,   // 14*512 bf16 B-frags
    const float*    __restrict__ nw,            // (27,)
    unsigned short* __restrict__ outbuf,        // (B,NN,16) bf16 pre-BN sorted
    float*          __restrict__ stats)         // [16][32] striped accumulators
{
    int lane = threadIdx.x & 63;
    int wv = threadIdx.x >> 6;
    int m = lane & 15, quad = lane >> 4;       // compute-phase layout
    int v = lane & 31, h = lane >> 5;          // rank-phase layout
    int wid = blockIdx.x * 4 + wv;             // flat wave id [0, 8192)

    __shared__ int   jj[4][32][29];            // stride 29: conflict-minimal
    __shared__ float obuf[4][32][17];          // epilogue transpose staging
    __shared__ float rrl[4][32];
    __shared__ float red[4][32];
    __shared__ float lnw[27];

    if (threadIdx.x < 27) lnw[threadIdx.x] = nw[threadIdx.x];

    // B-fragments: loaded once per wave, held in registers
    bf16x8 bfr[14];
    #pragma unroll
    for (int i = 0; i < 14; i++)
        bfr[i] = *(const bf16x8*)(wfrag + i * 512 + lane * 8);
    __syncthreads();

    float psum = 0.f, psq = 0.f;
    int coff = (quad & 1) << 3;

    for (int pb = wid; pb < NP32; pb += 4 * NBLKC) {
        int b = pb >> 11;                  // 2048 pair-tiles per batch
        int r0 = (pb & 2047) << 5;         // 32 ranks per pair
        int cnt = nvv[b];
        if (r0 >= cnt) continue;

        const int2* mb = mwb + (size_t)b * NW;
        const unsigned short* fb = sfeats + (size_t)b * NS * 16;
        const int2* sr = srow + (size_t)b * NN;

        // ---- rank phase: slot = (voxel v, column c = 2t + h), c in [0,9) ----
        int Rv = r0 + v;
        bool vld = Rv < cnt;
        int lin = vld ? sr[Rv].x : 0;
        int x = lin >> 12, y = (lin >> 6) & 63, z = lin & 63;
        int zb = z & 31;
        float nc = 0.f;
        #pragma unroll
        for (int t = 0; t < 5; t++) {
            int c = 2 * t + h;
            bool cok = c < 9;
            int cc = cok ? c : 0;
            int dx = cc / 3 - 1, dy = cc % 3 - 1;
            int nx = x + dx, ny = y + dy;
            bool colok = cok & ((unsigned)nx < 64u) & ((unsigned)ny < 64u);
            int wdi = colok ? (((nx << 12) + (ny << 6) + z) >> 5) : 0;

            int2 mw = make_int2(0, 0);
            if (vld & colok) mw = mb[wdi];
            // rare 2nd word when z-1/z+1 crosses the 32-bit boundary
            bool need2 = vld & colok & (((zb == 0) & (z > 0)) | ((zb == 31) & (z < 63)));
            int w2 = wdi + ((zb == 0) ? -1 : 1);
            int2 mw2 = make_int2(0, 0);
            if (need2) mw2 = mb[w2];

            #pragma unroll
            for (int dz = -1; dz <= 1; dz++) {
                int zz = z + dz;
                bool zok = (unsigned)zz < 64u;
                bool same = (dz == 0) | ((dz < 0) ? (zb != 0) : (zb != 31));
                int2 word = same ? mw : mw2;
                int bb = zz & 31;
                uint32_t wm = (uint32_t)word.x;
                bool hit = vld & colok & zok & ((wm >> bb) & 1u);
                int rnk = word.y + __popc(wm & ((1u << bb) - 1u));
                int off = cc * 3 + dz + 1;
                int jv = hit ? rnk : NN;
                if (cok) {
                    jj[wv][v][off] = jv;
                    nc += hit ? lnw[off] : 0.f;
                }
            }
        }
        nc += __shfl_xor(nc, 32, 64);
        if (lane < 32) rrl[wv][v] = 1.f / (1.f + fabsf(nc));

        // ---- compute phase: 28 gathers + 28 MFMAs (two independent chains) ----
        f32x4 acc0 = {0.f, 0.f, 0.f, 0.f};
        f32x4 acc1 = {0.f, 0.f, 0.f, 0.f};
        #pragma unroll
        for (int i = 0; i < 14; i++) {
            int off = 2 * i + (quad >> 1);
            int idx = off < 27 ? off : 28;
            int j0 = jj[wv][m][idx];      j0 = (off < 27) ? j0 : NN;
            int j1 = jj[wv][m + 16][idx]; j1 = (off < 27) ? j1 : NN;
            bf16x8 a0 = *(const bf16x8*)(fb + (size_t)j0 * 16 + coff);
            bf16x8 a1 = *(const bf16x8*)(fb + (size_t)j1 * 16 + coff);
            acc0 = __builtin_amdgcn_mfma_f32_16x16x32_bf16(a0, bfr[i], acc0, 0, 0, 0);
            acc1 = __builtin_amdgcn_mfma_f32_16x16x32_bf16(a1, bfr[i], acc1, 0, 0, 0);
        }

        // ---- epilogue: stage D[row][ch] tile in LDS (same-wave, no barrier),
        //      then one coalesced 1KB store ----
        #pragma unroll
        for (int hh = 0; hh < 2; hh++) {
            #pragma unroll
            for (int r4 = 0; r4 < 4; r4++) {
                int row = (hh << 4) + (quad << 2) + r4;
                float tval = (hh ? acc1[r4] : acc0[r4]) * rrl[wv][row];
                psum += tval; psq += tval * tval;
                obuf[wv][row][m] = tval;
            }
        }
        // lane (orow = lane&31, half = lane>>5) stores 8 channels (16B)
        {
            int orow = v;
            int Rr = r0 + orow;
            if (Rr < cnt) {
                const float* src = &obuf[wv][orow][h * 8];
                uint4 val = make_uint4(pk2(src[0], src[1]), pk2(src[2], src[3]),
                                       pk2(src[4], src[5]), pk2(src[6], src[7]));
                *(uint4*)(outbuf + ((size_t)b * NN + Rr) * 16 + h * 8) = val;
            }
        }
    }

    // ---- BN partial stats: block reduce, striped atomics ----
    psum += __shfl_xor(psum, 16, 64); psum += __shfl_xor(psum, 32, 64);
    psq  += __shfl_xor(psq, 16, 64);  psq  += __shfl_xor(psq, 32, 64);
    if (lane < 16) { red[wv][lane] = psum; red[wv][16 + lane] = psq; }
    __syncthreads();
    if (threadIdx.x < 32) {
        float vv = red[0][threadIdx.x] + red[1][threadIdx.x] +
                   red[2][threadIdx.x] + red[3][threadIdx.x];
        atomicAdd(&stats[(blockIdx.x & 15) * 32 + threadIdx.x], vv);
    }
}

// ---------------------------------------------------------------------------
// shared helper: derive per-channel scale/bias from striped stats into LDS
// ---------------------------------------------------------------------------
__device__ __forceinline__ void compute_sb(
    const float* __restrict__ stats, const int* __restrict__ nvv,
    const float* __restrict__ gamma, const float* __restrict__ beta,
    float* sbs /*LDS[32]*/, float* sums /*LDS[32]*/)
{
    int tid = threadIdx.x;
    if (tid < 32) {
        float v = 0.f;
        #pragma unroll
        for (int s = 0; s < 16; s++) v += stats[s * 32 + tid];
        sums[tid] = v;
    }
    __syncthreads();
    if (tid < 16) {
        float cnt = 0.f;
        #pragma unroll
        for (int b = 0; b < NB; b++) cnt += (float)nvv[b];
        float mean = sums[tid] / cnt;
        float var  = fmaxf(sums[16 + tid] / cnt - mean * mean, 0.f);
        float scv = gamma[tid] * rsqrtf(var + EPSC);
        sbs[tid]      = scv;
        sbs[16 + tid] = beta[tid] - mean * scv;
    }
    __syncthreads();
}

// ---------------------------------------------------------------------------
// K5: BN1+ReLU on sorted bf16 -> sorted bf16 (rows [cnt,NN] zeroed); sb fused
// ---------------------------------------------------------------------------
__global__ __launch_bounds__(256) void bnrelu_sorted_kernel(
    const unsigned short* __restrict__ in, const float* __restrict__ stats,
    const int* __restrict__ nvv,
    const float* __restrict__ gamma, const float* __restrict__ beta,
    unsigned short* __restrict__ outb)
{
    __shared__ float sbs[32];
    __shared__ float sums[32];
    compute_sb(stats, nvv, gamma, beta, sbs, sums);

    int b = blockIdx.y;
    int r = blockIdx.x * 256 + threadIdx.x;
    if (r > NN) return;
    int cnt = nvv[b];
    uint4 lo = make_uint4(0, 0, 0, 0), hi = lo;
    if (r < cnt) {
        const uint4* ip = (const uint4*)(in + ((size_t)b * NN + r) * 16);
        uint4 xl = ip[0], xh = ip[1];
        float y[16];
        #pragma unroll
        for (int c = 0; c < 16; c++) {
            unsigned u = (c < 8) ? ((const unsigned*)&xl)[c >> 1]
                                 : ((const unsigned*)&xh)[(c - 8) >> 1];
            unsigned short sv = (c & 1) ? (unsigned short)(u >> 16)
                                        : (unsigned short)(u & 0xffff);
            y[c] = fmaxf(fmaf(bf2f(sv), sbs[c], sbs[16 + c]), 0.f);
        }
        lo = make_uint4(pk2(y[0], y[1]), pk2(y[2], y[3]), pk2(y[4], y[5]), pk2(y[6], y[7]));
        hi = make_uint4(pk2(y[8], y[9]), pk2(y[10], y[11]), pk2(y[12], y[13]), pk2(y[14], y[15]));
    }
    unsigned short* op = outb + ((size_t)b * NS + r) * 16;
    *(uint4*)op       = lo;
    *(uint4*)(op + 8) = hi;
}

// ---------------------------------------------------------------------------
// K7: final BN2+ReLU; scatter valid sorted rows to original order, zero rest
// ---------------------------------------------------------------------------
__global__ __launch_bounds__(256) void final_scatter_kernel(
    const unsigned short* __restrict__ in,     // (B,NN,16) bf16 pre-BN sorted
    const int2* __restrict__ srow,
    const float* __restrict__ stats, const int* __restrict__ nvv,
    const float* __restrict__ gamma, const float* __restrict__ beta,
    float* __restrict__ out)
{
    __shared__ float sbs[32];
    __shared__ float sums[32];
    compute_sb(stats, nvv, gamma, beta, sbs, sums);

    int b = blockIdx.y;
    int r = blockIdx.x * 256 + threadIdx.x;
    int cnt = nvv[b];
    if (r < cnt) {
        const uint4* ip = (const uint4*)(in + ((size_t)b * NN + r) * 16);
        uint4 xl = ip[0], xh = ip[1];
        float y[16];
        #pragma unroll
        for (int c = 0; c < 16; c++) {
            unsigned u = (c < 8) ? ((const unsigned*)&xl)[c >> 1]
                                 : ((const unsigned*)&xh)[(c - 8) >> 1];
            unsigned short sv = (c & 1) ? (unsigned short)(u >> 16)
                                        : (unsigned short)(u & 0xffff);
            y[c] = fmaxf(fmaf(bf2f(sv), sbs[c], sbs[16 + c]), 0.f);
        }
        int n = srow[(size_t)b * NN + r].y;
        float4* op = (float4*)(out + ((size_t)b * NN + n) * 16);
        op[0] = make_float4(y[0],  y[1],  y[2],  y[3]);
        op[1] = make_float4(y[4],  y[5],  y[6],  y[7]);
        op[2] = make_float4(y[8],  y[9],  y[10], y[11]);
        op[3] = make_float4(y[12], y[13], y[14], y[15]);
    } else {
        float4 z = make_float4(0.f, 0.f, 0.f, 0.f);
        float4* op = (float4*)(out + ((size_t)b * NN + r) * 16);
        op[0] = z; op[1] = z; op[2] = z; op[3] = z;
    }
}

// ---------------------------------------------------------------------------
extern "C" void kernel_launch(void* const* d_in, const int* in_sizes, int n_in,
                              void* d_out, int out_size, void* d_ws, size_t ws_size,
                              hipStream_t stream)
{
    const float* feats  = (const float*)d_in[0];
    const int*   xyz    = (const int*)d_in[1];
    const int*   nvv    = (const int*)d_in[2];
    const float* w0     = (const float*)d_in[3];
    const float* w1     = (const float*)d_in[4];
    const float* nw0    = (const float*)d_in[5];
    const float* nw1    = (const float*)d_in[6];
    const float* gamma0 = (const float*)d_in[7];
    const float* beta0  = (const float*)d_in[8];
    const float* gamma1 = (const float*)d_in[9];
    const float* beta1  = (const float*)d_in[10];
    float* out = (float*)d_out;

    char* ws = (char*)d_ws;
    uint32_t* mask    = (uint32_t*)ws;       ws += (size_t)NB * NW * 4;        // 256 KB (memset 0)
    float*    stats1  = (float*)ws;          ws += 16 * 32 * 4;                // 2 KB (memset 0)
    float*    stats2  = (float*)ws;          ws += 16 * 32 * 4;                // 2 KB (memset 0)
    int2*     mwb     = (int2*)ws;           ws += (size_t)NB * NW * 8;        // 512 KB
    int2*     srow    = (int2*)ws;           ws += (size_t)NB * NN * 8;        // 4 MB
    unsigned short* sfA = (unsigned short*)ws; ws += (size_t)NB * NS * 16 * 2; // 16.8 MB
    unsigned short* sfB = (unsigned short*)ws; ws += (size_t)NB * NS * 16 * 2; // 16.8 MB
    unsigned short* bufPre = (unsigned short*)ws; ws += (size_t)NB * NN * 16 * 2; // 16 MB
    unsigned short* wfr = (unsigned short*)ws; ws += (size_t)2 * 14 * 512 * 2; // 28 KB

    // zero mask + both striped stats accumulators in one memset
    hipMemsetAsync(mask, 0, (size_t)NB * NW * 4 + 16 * 32 * 4 * 2, stream);

    dim3 gridBN(NN / 256, NB);
    build_mask_kernel<<<gridBN, 256, 0, stream>>>(xyz, nvv, mask, w0, w1, wfr);
    scan_mask_kernel<<<NB, 256, 0, stream>>>(mask, mwb);
    perm_gather_kernel<<<gridBN, 256, 0, stream>>>(xyz, nvv, mwb, feats, srow, sfA);

    // Layer 1: sorted bf16 in -> sorted bf16 (pre-BN) out + stats1
    conv_mfma_kernel<<<NBLKC, 256, 0, stream>>>(
        sfA, srow, nvv, mwb, wfr, nw0, bufPre, stats1);
    bnrelu_sorted_kernel<<<dim3(NN / 256 + 1, NB), 256, 0, stream>>>(
        bufPre, stats1, nvv, gamma0, beta0, sfB);

    // Layer 2: sorted bf16 in -> sorted bf16 (pre-BN) out + stats2
    conv_mfma_kernel<<<NBLKC, 256, 0, stream>>>(
        sfB, srow, nvv, mwb, wfr + 14 * 512, nw1, bufPre, stats2);

    // Final: BN2+ReLU, scatter to original order, zero invalid rows
    final_scatter_kernel<<<dim3(NN / 256, NB), 256, 0, stream>>>(
        bufPre, srow, stats2, nvv, gamma1, beta1, out);
}